// Round 6
// baseline (178.758 us; speedup 1.0000x reference)
//
#include <hip/hip_runtime.h>
#include <math.h>

#define S_LEN 2048
#define BATCH 2
#define DM 1024
#define NH 16
#define DH 64
#define EPS 1e-6f

typedef __attribute__((ext_vector_type(8))) short bf16x8;
typedef __attribute__((ext_vector_type(4))) float f32x4;

__device__ __forceinline__ unsigned short f2bf(float f) {
    unsigned u = __float_as_uint(f);
    u = (u + 0x7fffu + ((u >> 16) & 1u)) >> 16;
    return (unsigned short)u;
}
__device__ __forceinline__ float2 bf2f2(unsigned u) {
    float2 r;
    r.x = __uint_as_float(u << 16);
    r.y = __uint_as_float(u & 0xFFFF0000u);
    return r;
}
__device__ __forceinline__ void unpack8(uint4 u, float* f) {
    float2 a = bf2f2(u.x), b = bf2f2(u.y), c = bf2f2(u.z), d = bf2f2(u.w);
    f[0] = a.x; f[1] = a.y; f[2] = b.x; f[3] = b.y;
    f[4] = c.x; f[5] = c.y; f[6] = d.x; f[7] = d.y;
}
__device__ __forceinline__ void load16(const void* g, void* l) {
    __builtin_amdgcn_global_load_lds(
        (const __attribute__((address_space(1))) unsigned int*)g,
        (__attribute__((address_space(3))) unsigned int*)l,
        16, 0, 0);
}

// ---------------- fp32 -> bf16, flat grid ----------------
__global__ __launch_bounds__(256) void cvt_flat(
    const float* __restrict__ x,
    const float* __restrict__ wq, const float* __restrict__ wk,
    const float* __restrict__ wv, const float* __restrict__ wo,
    unsigned short* __restrict__ x_bf,
    unsigned short* __restrict__ wq_bf, unsigned short* __restrict__ wk_bf,
    unsigned short* __restrict__ wv_bf, unsigned short* __restrict__ wo_bf)
{
    int u = blockIdx.x * 256 + threadIdx.x;   // 0 .. 1048575
    const float* s;
    unsigned short* d;
    int off;
    if (u < 524288) {
        s = x; d = x_bf; off = u;
    } else {
        int v = u - 524288;
        int w = v >> 17;          // 0..3
        off = v & 131071;
        s = (w == 0) ? wq : (w == 1) ? wk : (w == 2) ? wv : wo;
        d = (w == 0) ? wq_bf : (w == 1) ? wk_bf : (w == 2) ? wv_bf : wo_bf;
    }
    float4 a = ((const float4*)s)[2 * off];
    float4 b = ((const float4*)s)[2 * off + 1];
    uint4 o;
    o.x = (unsigned)f2bf(a.x) | ((unsigned)f2bf(a.y) << 16);
    o.y = (unsigned)f2bf(a.z) | ((unsigned)f2bf(a.w) << 16);
    o.z = (unsigned)f2bf(b.x) | ((unsigned)f2bf(b.y) << 16);
    o.w = (unsigned)f2bf(b.z) | ((unsigned)f2bf(b.w) << 16);
    ((uint4*)d)[off] = o;
}

// ---------------- MFMA GEMM qkv: 128x128 tile, BK=64 (unchanged) ----------
__global__ __launch_bounds__(256) void gemm_qkv(
    const unsigned short* __restrict__ A,
    const unsigned short* __restrict__ W0, const unsigned short* __restrict__ W1,
    const unsigned short* __restrict__ W2,
    const float* __restrict__ B0, const float* __restrict__ B1, const float* __restrict__ B2,
    unsigned short* __restrict__ O0, unsigned short* __restrict__ O1,
    unsigned short* __restrict__ O2,
    int M, int N, int K, int act_mask)
{
    const int z = blockIdx.z;
    const unsigned short* W = (z == 0) ? W0 : (z == 1) ? W1 : W2;
    const float* bias       = (z == 0) ? B0 : (z == 1) ? B1 : B2;
    unsigned short* O       = (z == 0) ? O0 : (z == 1) ? O1 : O2;
    const bool act = (act_mask >> z) & 1;

    __shared__ __align__(16) unsigned short AsU[128 * 64];
    __shared__ __align__(16) unsigned short BsU[128 * 64];

    const int tid = threadIdx.x;
    const int wave = tid >> 6;
    const int lane = tid & 63;
    const int quad = lane >> 4;
    const int lm = lane & 15;
    const int wr = wave >> 1, wc = wave & 1;

    const int rowBase = blockIdx.y * 128;
    const int colBase = blockIdx.x * 128;

    const int cS = (lane & 7) ^ ((lane >> 3) & 7);
    const unsigned short* Ag[4];
    const unsigned short* Wg[4];
    unsigned short* lA[4];
    unsigned short* lB[4];
#pragma unroll
    for (int i = 0; i < 4; ++i) {
        int rS = (wave * 4 + i) * 8 + (lane >> 3);
        Ag[i] = A + (size_t)(rowBase + rS) * K + cS * 8;
        Wg[i] = W + (size_t)(colBase + rS) * K + cS * 8;
        lA[i] = AsU + (size_t)((wave * 4 + i) * 64) * 8;
        lB[i] = BsU + (size_t)((wave * 4 + i) * 64) * 8;
    }

    const unsigned short* pA[4][2];
    const unsigned short* pB[4][2];
#pragma unroll
    for (int i = 0; i < 4; ++i) {
        int rA = wr * 64 + i * 16 + lm;
        int rB = wc * 64 + i * 16 + lm;
#pragma unroll
        for (int ks = 0; ks < 2; ++ks) {
            pA[i][ks] = AsU + (size_t)(rA * 8 + ((ks * 4 + quad) ^ (rA & 7))) * 8;
            pB[i][ks] = BsU + (size_t)(rB * 8 + ((ks * 4 + quad) ^ (rB & 7))) * 8;
        }
    }

    f32x4 acc[4][4];
#pragma unroll
    for (int i = 0; i < 4; ++i)
#pragma unroll
        for (int j = 0; j < 4; ++j)
            acc[i][j] = (f32x4){0.f, 0.f, 0.f, 0.f};

    for (int k0 = 0; k0 < K; k0 += 64) {
#pragma unroll
        for (int i = 0; i < 4; ++i) {
            load16(Ag[i] + k0, lA[i]);
            load16(Wg[i] + k0, lB[i]);
        }
        __syncthreads();
#pragma unroll
        for (int ks = 0; ks < 2; ++ks) {
            bf16x8 aF[4], bF[4];
#pragma unroll
            for (int i = 0; i < 4; ++i) {
                aF[i] = *(const bf16x8*)pA[i][ks];
                bF[i] = *(const bf16x8*)pB[i][ks];
            }
#pragma unroll
            for (int i = 0; i < 4; ++i)
#pragma unroll
                for (int j = 0; j < 4; ++j)
                    acc[i][j] = __builtin_amdgcn_mfma_f32_16x16x32_bf16(aF[i], bF[j], acc[i][j], 0, 0, 0);
        }
        __syncthreads();
    }

#pragma unroll
    for (int j = 0; j < 4; ++j) {
        const int col = colBase + wc * 64 + j * 16 + lm;
        const float bc = bias[col];
#pragma unroll
        for (int i = 0; i < 4; ++i) {
            const int row0 = rowBase + wr * 64 + i * 16 + quad * 4;
#pragma unroll
            for (int reg = 0; reg < 4; ++reg) {
                float v = acc[i][j][reg] + bc;
                if (act) v = (v > 0.0f) ? (v + 1.0f) : __expf(v);
                O[(size_t)(row0 + reg) * N + col] = f2bf(v);
            }
        }
    }
}

// -------- kv partials: wave-private compute + in-block reduction ----------
__global__ __launch_bounds__(256) void kv_part_kernel(
    const unsigned short* __restrict__ kf, const unsigned short* __restrict__ vv,
    float* __restrict__ kv_part, float* __restrict__ ksum_part)
{
    const int bh = blockIdx.x;
    const int b = bh >> 4, h = bh & 15;
    const int tid = threadIdx.x;
    const int wave = tid >> 6, lane = tid & 63;
    const int blk = blockIdx.y;             // 0..3
    const int posBase = (blk * 4 + wave) * 128;

    __shared__ __align__(16) float smem[17408];
    float (*Ks)[2][16][68] = (float (*)[2][16][68])smem;
    float (*Vs)[2][16][68] = (float (*)[2][16][68])(smem + 8704);

    const int pos_l = lane >> 3;
    const int f0 = (lane & 7) * 8;
    const int r0 = pos_l * 8;
    const int c0 = f0;

    float acc[8][8] = {};
    float srow[8] = {};

    for (int st = 0; st < 8; ++st) {
        const int buf = st & 1;
        size_t g0 = ((size_t)(b * S_LEN + posBase + st * 16 + pos_l)) * DM + h * DH + f0;
        size_t g1 = g0 + (size_t)8 * DM;
        uint4 ka = *(const uint4*)(kf + g0);
        uint4 kb = *(const uint4*)(kf + g1);
        uint4 va = *(const uint4*)(vv + g0);
        uint4 vb = *(const uint4*)(vv + g1);
        float kaf[8], kbf[8], vaf[8], vbf[8];
        unpack8(ka, kaf); unpack8(kb, kbf); unpack8(va, vaf); unpack8(vb, vbf);
#pragma unroll
        for (int j = 0; j < 8; ++j) srow[j] += kaf[j] + kbf[j];
        *(float4*)&Ks[wave][buf][pos_l][f0]         = make_float4(kaf[0], kaf[1], kaf[2], kaf[3]);
        *(float4*)&Ks[wave][buf][pos_l][f0 + 4]     = make_float4(kaf[4], kaf[5], kaf[6], kaf[7]);
        *(float4*)&Ks[wave][buf][pos_l + 8][f0]     = make_float4(kbf[0], kbf[1], kbf[2], kbf[3]);
        *(float4*)&Ks[wave][buf][pos_l + 8][f0 + 4] = make_float4(kbf[4], kbf[5], kbf[6], kbf[7]);
        *(float4*)&Vs[wave][buf][pos_l][f0]         = make_float4(vaf[0], vaf[1], vaf[2], vaf[3]);
        *(float4*)&Vs[wave][buf][pos_l][f0 + 4]     = make_float4(vaf[4], vaf[5], vaf[6], vaf[7]);
        *(float4*)&Vs[wave][buf][pos_l + 8][f0]     = make_float4(vbf[0], vbf[1], vbf[2], vbf[3]);
        *(float4*)&Vs[wave][buf][pos_l + 8][f0 + 4] = make_float4(vbf[4], vbf[5], vbf[6], vbf[7]);
#pragma unroll 4
        for (int q = 0; q < 16; ++q) {
            float4 a0 = *(const float4*)&Ks[wave][buf][q][r0];
            float4 a1 = *(const float4*)&Ks[wave][buf][q][r0 + 4];
            float4 b0 = *(const float4*)&Vs[wave][buf][q][c0];
            float4 b1 = *(const float4*)&Vs[wave][buf][q][c0 + 4];
            float aa[8] = {a0.x, a0.y, a0.z, a0.w, a1.x, a1.y, a1.z, a1.w};
            float bb[8] = {b0.x, b0.y, b0.z, b0.w, b1.x, b1.y, b1.z, b1.w};
#pragma unroll
            for (int i = 0; i < 8; ++i)
#pragma unroll
                for (int j = 0; j < 8; ++j)
                    acc[i][j] += aa[i] * bb[j];
        }
    }

#pragma unroll
    for (int j = 0; j < 8; ++j) {
        srow[j] += __shfl_xor(srow[j], 8);
        srow[j] += __shfl_xor(srow[j], 16);
        srow[j] += __shfl_xor(srow[j], 32);
    }

    __syncthreads();
    float* red = smem;
    float* ksred = smem + 16384;
#pragma unroll
    for (int j = 0; j < 8; ++j) {
        *(float4*)&red[wave * 4096 + (c0 + j) * 64 + r0] =
            make_float4(acc[0][j], acc[1][j], acc[2][j], acc[3][j]);
        *(float4*)&red[wave * 4096 + (c0 + j) * 64 + r0 + 4] =
            make_float4(acc[4][j], acc[5][j], acc[6][j], acc[7][j]);
    }
    if (pos_l == 0) {
        *(float4*)&ksred[wave * 64 + f0]     = make_float4(srow[0], srow[1], srow[2], srow[3]);
        *(float4*)&ksred[wave * 64 + f0 + 4] = make_float4(srow[4], srow[5], srow[6], srow[7]);
    }
    __syncthreads();

    float* outp = kv_part + ((size_t)bh * 4 + blk) * 4096;
    const int base = tid * 16;
#pragma unroll
    for (int g = 0; g < 4; ++g) {
        float4 s0 = *(const float4*)&red[base + g * 4];
        float4 s1 = *(const float4*)&red[4096 + base + g * 4];
        float4 s2 = *(const float4*)&red[8192 + base + g * 4];
        float4 s3 = *(const float4*)&red[12288 + base + g * 4];
        float4 o = make_float4(s0.x + s1.x + s2.x + s3.x,
                               s0.y + s1.y + s2.y + s3.y,
                               s0.z + s1.z + s2.z + s3.z,
                               s0.w + s1.w + s2.w + s3.w);
        *(float4*)&outp[base + g * 4] = o;
    }
    if (tid < 64) {
        float t = ksred[tid] + ksred[64 + tid] + ksred[128 + tid] + ksred[192 + tid];
        ksum_part[((size_t)bh * 4 + blk) * 64 + tid] = t;
    }
}

// -------- reduce 4 partials -> kvT bf16 + ksum fp32 (tiny, 32 blocks) -----
__global__ __launch_bounds__(256) void kv_reduce_kernel(
    const float* __restrict__ kv_part, const float* __restrict__ ksum_part,
    unsigned short* __restrict__ kvT_bf, float* __restrict__ ksum)
{
    const int bh = blockIdx.x;
    const int tid = threadIdx.x;
    const float* base = kv_part + (size_t)bh * 4 * 4096 + tid * 16;
    float s[16];
#pragma unroll
    for (int g = 0; g < 4; ++g) {
        float4 p0 = *(const float4*)(base + g * 4);
        float4 p1 = *(const float4*)(base + 4096 + g * 4);
        float4 p2 = *(const float4*)(base + 8192 + g * 4);
        float4 p3 = *(const float4*)(base + 12288 + g * 4);
        s[g * 4 + 0] = p0.x + p1.x + p2.x + p3.x;
        s[g * 4 + 1] = p0.y + p1.y + p2.y + p3.y;
        s[g * 4 + 2] = p0.z + p1.z + p2.z + p3.z;
        s[g * 4 + 3] = p0.w + p1.w + p2.w + p3.w;
    }
    unsigned short us[16];
#pragma unroll
    for (int i = 0; i < 16; ++i) us[i] = f2bf(s[i]);
    uint4 o0, o1;
    o0.x = (unsigned)us[0]  | ((unsigned)us[1]  << 16);
    o0.y = (unsigned)us[2]  | ((unsigned)us[3]  << 16);
    o0.z = (unsigned)us[4]  | ((unsigned)us[5]  << 16);
    o0.w = (unsigned)us[6]  | ((unsigned)us[7]  << 16);
    o1.x = (unsigned)us[8]  | ((unsigned)us[9]  << 16);
    o1.y = (unsigned)us[10] | ((unsigned)us[11] << 16);
    o1.z = (unsigned)us[12] | ((unsigned)us[13] << 16);
    o1.w = (unsigned)us[14] | ((unsigned)us[15] << 16);
    uint4* dst = (uint4*)(kvT_bf + (size_t)bh * (DH * DH) + tid * 16);
    dst[0] = o0; dst[1] = o1;
    if (tid < DH) {
        const float* kq = ksum_part + (size_t)bh * 4 * 64 + tid;
        ksum[bh * DH + tid] = kq[0] + kq[64] + kq[128] + kq[192];
    }
}

// -------- fused attend + output projection --------------------------------
// out[s][n] = sum_h [ (qf[s][h,:] @ kvT_h^T) / den_h(s) ] @ wo[n][h,:] + bo
// Block: 64 s-rows x 128 n-cols; K-loop over 16 heads. P round-trips LDS as
// bf16 (identical f2bf rounding and k-order as the unfused path -> output is
// bit-identical to round-5's).
__global__ __launch_bounds__(256) void attend_out(
    const unsigned short* __restrict__ qf,    // [4096][1024] bf16
    const unsigned short* __restrict__ kvT,   // [32][64e][64d] bf16
    const float* __restrict__ ksum,           // [32][64]
    const unsigned short* __restrict__ wo,    // [1024][1024] bf16
    const float* __restrict__ bo,
    float* __restrict__ out)                  // [4096][1024] fp32
{
    const int rowBase = blockIdx.y * 64;
    const int colBase = blockIdx.x * 128;
    const int b = blockIdx.y >> 5;            // 32 row-blocks per batch

    __shared__ __align__(16) unsigned short Qs[64 * 64];    // 8 KB
    __shared__ __align__(16) unsigned short Ts[64 * 64];    // 8 KB
    __shared__ __align__(16) unsigned short Ws[128 * 64];   // 16 KB
    __shared__ __align__(16) unsigned short Ps[64 * 64];    // 8 KB
    __shared__ __align__(16) float ks_s[64];
    __shared__ float den_part[4][64];

    const int tid = threadIdx.x;
    const int wave = tid >> 6, lane = tid & 63;
    const int quad = lane >> 4, lm = lane & 15;
    const int wr = wave >> 1, wc = wave & 1;

    // staging descriptors (h-invariant parts)
    const unsigned short* qSrc[2];
    unsigned short* qDst[2];
    const unsigned short* tSrc[2];
    unsigned short* tDst[2];
    const unsigned short* wSrc[4];
    unsigned short* wDst[4];
#pragma unroll
    for (int i = 0; i < 2; ++i) {
        int slot = (wave * 2 + i) * 64 + lane;
        int r = slot >> 3, c = (slot & 7) ^ (r & 7);
        qSrc[i] = qf + (size_t)(rowBase + r) * DM + c * 8;
        qDst[i] = Qs + (size_t)((wave * 2 + i) * 64) * 8;
        tSrc[i] = kvT + (size_t)(b * NH) * (DH * DH) + r * DH + c * 8;
        tDst[i] = Ts + (size_t)((wave * 2 + i) * 64) * 8;
    }
#pragma unroll
    for (int i = 0; i < 4; ++i) {
        int slot = (wave * 4 + i) * 64 + lane;
        int r = slot >> 3, c = (slot & 7) ^ (r & 7);
        wSrc[i] = wo + (size_t)(colBase + r) * DM + c * 8;
        wDst[i] = Ws + (size_t)((wave * 4 + i) * 64) * 8;
    }

    // P-MFMA fragment pointers (wave handles s-rows [wave*16, +16))
    const unsigned short* pQ[2];
    const unsigned short* pT[4][2];
    {
        int r = wave * 16 + lm;
#pragma unroll
        for (int ks = 0; ks < 2; ++ks)
            pQ[ks] = Qs + (size_t)(r * 8 + ((ks * 4 + quad) ^ (r & 7))) * 8;
#pragma unroll
        for (int tj = 0; tj < 4; ++tj) {
            int e = tj * 16 + lm;
#pragma unroll
            for (int ks = 0; ks < 2; ++ks)
                pT[tj][ks] = Ts + (size_t)(e * 8 + ((ks * 4 + quad) ^ (e & 7))) * 8;
        }
    }
    // out-MFMA fragment pointers
    const unsigned short* pP[2][2];
    const unsigned short* pW[4][2];
#pragma unroll
    for (int i = 0; i < 2; ++i) {
        int r = wr * 32 + i * 16 + lm;
#pragma unroll
        for (int ks = 0; ks < 2; ++ks)
            pP[i][ks] = Ps + (size_t)(r * 8 + ((ks * 4 + quad) ^ (r & 7))) * 8;
    }
#pragma unroll
    for (int j = 0; j < 4; ++j) {
        int n = wc * 64 + j * 16 + lm;
#pragma unroll
        for (int ks = 0; ks < 2; ++ks)
            pW[j][ks] = Ws + (size_t)(n * 8 + ((ks * 4 + quad) ^ (n & 7))) * 8;
    }

    // den-partial descriptor: thread t covers s = t&63, d-range q*16..+16
    const int ds = tid & 63, dq = tid >> 6;
    const unsigned short* dQ0 = Qs + (size_t)(ds * 8 + ((dq * 2) ^ (ds & 7))) * 8;
    const unsigned short* dQ1 = Qs + (size_t)(ds * 8 + ((dq * 2 + 1) ^ (ds & 7))) * 8;

    // P-scatter descriptor: lane writes (srow = wave*16 + quad*4 + reg, e = tj*16+lm)
    unsigned short* sP[4][4];
#pragma unroll
    for (int reg = 0; reg < 4; ++reg) {
        int srow = wave * 16 + quad * 4 + reg;
#pragma unroll
        for (int tj = 0; tj < 4; ++tj) {
            int e = tj * 16 + lm;
            sP[reg][tj] = Ps + (size_t)(srow * 8 + ((e >> 3) ^ (srow & 7))) * 8 + (e & 7);
        }
    }

    f32x4 oacc[2][4];
#pragma unroll
    for (int i = 0; i < 2; ++i)
#pragma unroll
        for (int j = 0; j < 4; ++j)
            oacc[i][j] = (f32x4){0.f, 0.f, 0.f, 0.f};

    for (int h = 0; h < NH; ++h) {
        // ---- stage qf_h, kvT_h, wo_h ----
#pragma unroll
        for (int i = 0; i < 2; ++i) {
            load16(qSrc[i] + h * DH, qDst[i]);
            load16(tSrc[i] + h * (DH * DH), tDst[i]);
        }
#pragma unroll
        for (int i = 0; i < 4; ++i)
            load16(wSrc[i] + h * DH, wDst[i]);
        if (tid < 16)
            *(float4*)&ks_s[tid * 4] =
                *(const float4*)&ksum[(b * NH + h) * DH + tid * 4];
        __syncthreads();   // B1: LDS tiles + ks_s ready; prev out-MFMA reads done

        // ---- den partials (VALU) ----
        {
            uint4 u0 = *(const uint4*)dQ0;
            uint4 u1 = *(const uint4*)dQ1;
            float f0[8], f1[8];
            unpack8(u0, f0); unpack8(u1, f1);
            const float* kss = &ks_s[dq * 16];
            float d = 0.f;
#pragma unroll
            for (int j = 0; j < 8; ++j) d += f0[j] * kss[j] + f1[j] * kss[8 + j];
            den_part[dq][ds] = d;
        }

        // ---- P = qf_h @ kvT_h^T (per wave: 16 s-rows x 64 e) ----
        f32x4 pacc[4];
#pragma unroll
        for (int tj = 0; tj < 4; ++tj) pacc[tj] = (f32x4){0.f, 0.f, 0.f, 0.f};
#pragma unroll
        for (int ks = 0; ks < 2; ++ks) {
            bf16x8 aF = *(const bf16x8*)pQ[ks];
#pragma unroll
            for (int tj = 0; tj < 4; ++tj) {
                bf16x8 bF = *(const bf16x8*)pT[tj][ks];
                pacc[tj] = __builtin_amdgcn_mfma_f32_16x16x32_bf16(aF, bF, pacc[tj], 0, 0, 0);
            }
        }
        __syncthreads();   // B2: den_part visible

        // ---- scale by 1/den, bf16, scatter to Ps ----
        float inv[4];
#pragma unroll
        for (int reg = 0; reg < 4; ++reg) {
            int srow = wave * 16 + quad * 4 + reg;
            float den = den_part[0][srow] + den_part[1][srow] +
                        den_part[2][srow] + den_part[3][srow];
            inv[reg] = 1.0f / fmaxf(den, EPS);
        }
#pragma unroll
        for (int tj = 0; tj < 4; ++tj)
#pragma unroll
            for (int reg = 0; reg < 4; ++reg)
                *sP[reg][tj] = f2bf(pacc[tj][reg] * inv[reg]);
        __syncthreads();   // B3: Ps ready

        // ---- out += att_h @ wo_h^T ----
#pragma unroll
        for (int ks = 0; ks < 2; ++ks) {
            bf16x8 aF[2], bF[4];
#pragma unroll
            for (int i = 0; i < 2; ++i) aF[i] = *(const bf16x8*)pP[i][ks];
#pragma unroll
            for (int j = 0; j < 4; ++j) bF[j] = *(const bf16x8*)pW[j][ks];
#pragma unroll
            for (int i = 0; i < 2; ++i)
#pragma unroll
                for (int j = 0; j < 4; ++j)
                    oacc[i][j] = __builtin_amdgcn_mfma_f32_16x16x32_bf16(aF[i], bF[j], oacc[i][j], 0, 0, 0);
        }
    }

    // ---- epilogue ----
#pragma unroll
    for (int j = 0; j < 4; ++j) {
        const int col = colBase + wc * 64 + j * 16 + lm;
        const float bc = bo[col];
#pragma unroll
        for (int i = 0; i < 2; ++i) {
            const int row0 = rowBase + wr * 32 + i * 16 + quad * 4;
#pragma unroll
            for (int reg = 0; reg < 4; ++reg)
                out[(size_t)(row0 + reg) * DM + col] = oacc[i][j][reg] + bc;
        }
    }
}

extern "C" void kernel_launch(void* const* d_in, const int* in_sizes, int n_in,
                              void* d_out, int out_size, void* d_ws, size_t ws_size,
                              hipStream_t stream) {
    const float* x  = (const float*)d_in[0];
    const float* wq = (const float*)d_in[1];
    const float* bq = (const float*)d_in[2];
    const float* wk = (const float*)d_in[3];
    const float* bk = (const float*)d_in[4];
    const float* wv = (const float*)d_in[5];
    const float* bv = (const float*)d_in[6];
    const float* wo = (const float*)d_in[7];
    const float* bo = (const float*)d_in[8];
    float* out = (float*)d_out;

    const size_t ND  = (size_t)BATCH * S_LEN * DM;  // 4,194,304
    const size_t NDW = (size_t)DM * DM;             // 1,048,576
    const int BH = BATCH * NH;                      // 32

    unsigned short* x_bf   = (unsigned short*)d_ws;
    unsigned short* wq_bf  = x_bf + ND;
    unsigned short* wk_bf  = wq_bf + NDW;
    unsigned short* wv_bf  = wk_bf + NDW;
    unsigned short* wo_bf  = wv_bf + NDW;
    unsigned short* qf_bf  = wo_bf + NDW;
    unsigned short* kf_bf  = qf_bf + ND;
    unsigned short* vv_bf  = kf_bf + ND;
    unsigned short* kvT_bf = vv_bf + ND;                        // BH*4096 shorts
    float* kv_part   = (float*)(kvT_bf + (size_t)BH * DH * DH); // BH*4*4096 floats
    float* ksum_part = kv_part + (size_t)BH * 4 * 4096;         // BH*4*64
    float* ksum      = ksum_part + (size_t)BH * 4 * 64;         // BH*64

    const int M = BATCH * S_LEN;  // 4096

    // 1. fp32 -> bf16
    cvt_flat<<<4096, 256, 0, stream>>>(x, wq, wk, wv, wo,
                                       x_bf, wq_bf, wk_bf, wv_bf, wo_bf);

    // 2. q/k/v projections (elu+1 on q,k), BK=64
    gemm_qkv<<<dim3(DM / 128, M / 128, 3), 256, 0, stream>>>(
        x_bf, wq_bf, wk_bf, wv_bf, bq, bk, bv,
        qf_bf, kf_bf, vv_bf, M, DM, DM, 0b011);

    // 3. kv partials
    kv_part_kernel<<<dim3(BH, 4), 256, 0, stream>>>(kf_bf, vv_bf, kv_part, ksum_part);

    // 4. reduce -> kvT bf16 + ksum
    kv_reduce_kernel<<<BH, 256, 0, stream>>>(kv_part, ksum_part, kvT_bf, ksum);

    // 5. fused attend + output projection
    attend_out<<<dim3(DM / 128, M / 64), 256, 0, stream>>>(
        qf_bf, kvT_bf, ksum, wo_bf, bo, out);
}

// Round 8
// 171.903 us; speedup vs baseline: 1.0399x; 1.0399x over previous
//
#include <hip/hip_runtime.h>
#include <math.h>

#define S_LEN 2048
#define BATCH 2
#define DM 1024
#define NH 16
#define DH 64
#define EPS 1e-6f

typedef __attribute__((ext_vector_type(8))) short bf16x8;
typedef __attribute__((ext_vector_type(4))) float f32x4;

__device__ __forceinline__ unsigned short f2bf(float f) {
    unsigned u = __float_as_uint(f);
    u = (u + 0x7fffu + ((u >> 16) & 1u)) >> 16;
    return (unsigned short)u;
}
__device__ __forceinline__ float2 bf2f2(unsigned u) {
    float2 r;
    r.x = __uint_as_float(u << 16);
    r.y = __uint_as_float(u & 0xFFFF0000u);
    return r;
}
__device__ __forceinline__ void unpack8(uint4 u, float* f) {
    float2 a = bf2f2(u.x), b = bf2f2(u.y), c = bf2f2(u.z), d = bf2f2(u.w);
    f[0] = a.x; f[1] = a.y; f[2] = b.x; f[3] = b.y;
    f[4] = c.x; f[5] = c.y; f[6] = d.x; f[7] = d.y;
}
__device__ __forceinline__ void load16(const void* g, void* l) {
    __builtin_amdgcn_global_load_lds(
        (const __attribute__((address_space(1))) unsigned int*)g,
        (__attribute__((address_space(3))) unsigned int*)l,
        16, 0, 0);
}

// ---------------- fp32 -> bf16, flat grid ----------------
__global__ __launch_bounds__(256) void cvt_flat(
    const float* __restrict__ x,
    const float* __restrict__ wq, const float* __restrict__ wk,
    const float* __restrict__ wv, const float* __restrict__ wo,
    unsigned short* __restrict__ x_bf,
    unsigned short* __restrict__ wq_bf, unsigned short* __restrict__ wk_bf,
    unsigned short* __restrict__ wv_bf, unsigned short* __restrict__ wo_bf)
{
    int u = blockIdx.x * 256 + threadIdx.x;   // 0 .. 1048575
    const float* s;
    unsigned short* d;
    int off;
    if (u < 524288) {
        s = x; d = x_bf; off = u;
    } else {
        int v = u - 524288;
        int w = v >> 17;          // 0..3
        off = v & 131071;
        s = (w == 0) ? wq : (w == 1) ? wk : (w == 2) ? wv : wo;
        d = (w == 0) ? wq_bf : (w == 1) ? wk_bf : (w == 2) ? wv_bf : wo_bf;
    }
    float4 a = ((const float4*)s)[2 * off];
    float4 b = ((const float4*)s)[2 * off + 1];
    uint4 o;
    o.x = (unsigned)f2bf(a.x) | ((unsigned)f2bf(a.y) << 16);
    o.y = (unsigned)f2bf(a.z) | ((unsigned)f2bf(a.w) << 16);
    o.z = (unsigned)f2bf(b.x) | ((unsigned)f2bf(b.y) << 16);
    o.w = (unsigned)f2bf(b.z) | ((unsigned)f2bf(b.w) << 16);
    ((uint4*)d)[off] = o;
}

// ---------------- MFMA GEMM qkv: 128x128 tile, BK=64 ----------------------
// LDS swizzle: chunk c (8 bf16) of row r at slot r*8 + (c ^ (r&7)).
// Staging: slot s -> r=s>>3, c=(s&7)^((s>>3)&7); wave-uniform base + lane*16.
__global__ __launch_bounds__(256) void gemm_qkv(
    const unsigned short* __restrict__ A,
    const unsigned short* __restrict__ W0, const unsigned short* __restrict__ W1,
    const unsigned short* __restrict__ W2,
    const float* __restrict__ B0, const float* __restrict__ B1, const float* __restrict__ B2,
    unsigned short* __restrict__ O0, unsigned short* __restrict__ O1,
    unsigned short* __restrict__ O2,
    int M, int N, int K, int act_mask)
{
    const int z = blockIdx.z;
    const unsigned short* W = (z == 0) ? W0 : (z == 1) ? W1 : W2;
    const float* bias       = (z == 0) ? B0 : (z == 1) ? B1 : B2;
    unsigned short* O       = (z == 0) ? O0 : (z == 1) ? O1 : O2;
    const bool act = (act_mask >> z) & 1;

    __shared__ __align__(16) unsigned short AsU[128 * 64];  // 16 KB
    __shared__ __align__(16) unsigned short BsU[128 * 64];  // 16 KB

    const int tid = threadIdx.x;
    const int wave = tid >> 6;
    const int lane = tid & 63;
    const int quad = lane >> 4;
    const int lm = lane & 15;
    const int wr = wave >> 1, wc = wave & 1;

    const int rowBase = blockIdx.y * 128;
    const int colBase = blockIdx.x * 128;

    const int cS = (lane & 7) ^ ((lane >> 3) & 7);   // iter-invariant chunk
    const unsigned short* Ag[4];
    const unsigned short* Wg[4];
    unsigned short* lA[4];
    unsigned short* lB[4];
#pragma unroll
    for (int i = 0; i < 4; ++i) {
        int rS = (wave * 4 + i) * 8 + (lane >> 3);
        Ag[i] = A + (size_t)(rowBase + rS) * K + cS * 8;
        Wg[i] = W + (size_t)(colBase + rS) * K + cS * 8;
        lA[i] = AsU + (size_t)((wave * 4 + i) * 64) * 8;
        lB[i] = BsU + (size_t)((wave * 4 + i) * 64) * 8;
    }

    const unsigned short* pA[4][2];
    const unsigned short* pB[4][2];
#pragma unroll
    for (int i = 0; i < 4; ++i) {
        int rA = wr * 64 + i * 16 + lm;
        int rB = wc * 64 + i * 16 + lm;
#pragma unroll
        for (int ks = 0; ks < 2; ++ks) {
            pA[i][ks] = AsU + (size_t)(rA * 8 + ((ks * 4 + quad) ^ (rA & 7))) * 8;
            pB[i][ks] = BsU + (size_t)(rB * 8 + ((ks * 4 + quad) ^ (rB & 7))) * 8;
        }
    }

    f32x4 acc[4][4];
#pragma unroll
    for (int i = 0; i < 4; ++i)
#pragma unroll
        for (int j = 0; j < 4; ++j)
            acc[i][j] = (f32x4){0.f, 0.f, 0.f, 0.f};

    for (int k0 = 0; k0 < K; k0 += 64) {
#pragma unroll
        for (int i = 0; i < 4; ++i) {
            load16(Ag[i] + k0, lA[i]);
            load16(Wg[i] + k0, lB[i]);
        }
        __syncthreads();
#pragma unroll
        for (int ks = 0; ks < 2; ++ks) {
            bf16x8 aF[4], bF[4];
#pragma unroll
            for (int i = 0; i < 4; ++i) {
                aF[i] = *(const bf16x8*)pA[i][ks];
                bF[i] = *(const bf16x8*)pB[i][ks];
            }
#pragma unroll
            for (int i = 0; i < 4; ++i)
#pragma unroll
                for (int j = 0; j < 4; ++j)
                    acc[i][j] = __builtin_amdgcn_mfma_f32_16x16x32_bf16(aF[i], bF[j], acc[i][j], 0, 0, 0);
        }
        __syncthreads();
    }

#pragma unroll
    for (int j = 0; j < 4; ++j) {
        const int col = colBase + wc * 64 + j * 16 + lm;
        const float bc = bias[col];
#pragma unroll
        for (int i = 0; i < 4; ++i) {
            const int row0 = rowBase + wr * 64 + i * 16 + quad * 4;
#pragma unroll
            for (int reg = 0; reg < 4; ++reg) {
                float v = acc[i][j][reg] + bc;
                if (act) v = (v > 0.0f) ? (v + 1.0f) : __expf(v);
                O[(size_t)(row0 + reg) * N + col] = f2bf(v);
            }
        }
    }
}

// ---------------- out-proj GEMM: 64x128 tile, BK=64 -----------------------
__global__ __launch_bounds__(256) void gemm_out(
    const unsigned short* __restrict__ A,   // att bf16 [M x K]
    const unsigned short* __restrict__ W,   // wo bf16 [N x K]
    const float* __restrict__ bias,
    float* __restrict__ O, int M, int N, int K)
{
    __shared__ __align__(16) unsigned short AsU[64 * 64];    // 8 KB
    __shared__ __align__(16) unsigned short BsU[128 * 64];   // 16 KB

    const int tid = threadIdx.x;
    const int wave = tid >> 6;
    const int lane = tid & 63;
    const int quad = lane >> 4;
    const int lm = lane & 15;
    const int wr = wave >> 1, wc = wave & 1;

    const int rowBase = blockIdx.y * 64;
    const int colBase = blockIdx.x * 128;

    const int cS = (lane & 7) ^ ((lane >> 3) & 7);
    const unsigned short* Ag[2];
    const unsigned short* Wg[4];
    unsigned short* lA[2];
    unsigned short* lB[4];
#pragma unroll
    for (int i = 0; i < 2; ++i) {
        int rS = (wave * 2 + i) * 8 + (lane >> 3);
        Ag[i] = A + (size_t)(rowBase + rS) * K + cS * 8;
        lA[i] = AsU + (size_t)((wave * 2 + i) * 64) * 8;
    }
#pragma unroll
    for (int i = 0; i < 4; ++i) {
        int rS = (wave * 4 + i) * 8 + (lane >> 3);
        Wg[i] = W + (size_t)(colBase + rS) * K + cS * 8;
        lB[i] = BsU + (size_t)((wave * 4 + i) * 64) * 8;
    }

    const unsigned short* pA[2][2];
    const unsigned short* pB[4][2];
#pragma unroll
    for (int i = 0; i < 2; ++i) {
        int rA = wr * 32 + i * 16 + lm;
#pragma unroll
        for (int ks = 0; ks < 2; ++ks)
            pA[i][ks] = AsU + (size_t)(rA * 8 + ((ks * 4 + quad) ^ (rA & 7))) * 8;
    }
#pragma unroll
    for (int j = 0; j < 4; ++j) {
        int rB = wc * 64 + j * 16 + lm;
#pragma unroll
        for (int ks = 0; ks < 2; ++ks)
            pB[j][ks] = BsU + (size_t)(rB * 8 + ((ks * 4 + quad) ^ (rB & 7))) * 8;
    }

    f32x4 acc[2][4];
#pragma unroll
    for (int i = 0; i < 2; ++i)
#pragma unroll
        for (int j = 0; j < 4; ++j)
            acc[i][j] = (f32x4){0.f, 0.f, 0.f, 0.f};

    for (int k0 = 0; k0 < K; k0 += 64) {
#pragma unroll
        for (int i = 0; i < 2; ++i) load16(Ag[i] + k0, lA[i]);
#pragma unroll
        for (int i = 0; i < 4; ++i) load16(Wg[i] + k0, lB[i]);
        __syncthreads();
#pragma unroll
        for (int ks = 0; ks < 2; ++ks) {
            bf16x8 aF[2], bF[4];
#pragma unroll
            for (int i = 0; i < 2; ++i) aF[i] = *(const bf16x8*)pA[i][ks];
#pragma unroll
            for (int j = 0; j < 4; ++j) bF[j] = *(const bf16x8*)pB[j][ks];
#pragma unroll
            for (int i = 0; i < 2; ++i)
#pragma unroll
                for (int j = 0; j < 4; ++j)
                    acc[i][j] = __builtin_amdgcn_mfma_f32_16x16x32_bf16(aF[i], bF[j], acc[i][j], 0, 0, 0);
        }
        __syncthreads();
    }

#pragma unroll
    for (int j = 0; j < 4; ++j) {
        const int col = colBase + wc * 64 + j * 16 + lm;
        const float bc = bias[col];
#pragma unroll
        for (int i = 0; i < 2; ++i) {
            const int row0 = rowBase + wr * 32 + i * 16 + quad * 4;
#pragma unroll
            for (int reg = 0; reg < 4; ++reg)
                O[(size_t)(row0 + reg) * N + col] = acc[i][j][reg] + bc;
        }
    }
}

// -------- kv partials: wave-private compute + in-block reduction ----------
__global__ __launch_bounds__(256) void kv_part_kernel(
    const unsigned short* __restrict__ kf, const unsigned short* __restrict__ vv,
    float* __restrict__ kv_part, float* __restrict__ ksum_part)
{
    const int bh = blockIdx.x;
    const int b = bh >> 4, h = bh & 15;
    const int tid = threadIdx.x;
    const int wave = tid >> 6, lane = tid & 63;
    const int blk = blockIdx.y;             // 0..3
    const int posBase = (blk * 4 + wave) * 128;

    __shared__ __align__(16) float smem[17408];
    float (*Ks)[2][16][68] = (float (*)[2][16][68])smem;
    float (*Vs)[2][16][68] = (float (*)[2][16][68])(smem + 8704);

    const int pos_l = lane >> 3;
    const int f0 = (lane & 7) * 8;
    const int r0 = pos_l * 8;
    const int c0 = f0;

    float acc[8][8] = {};
    float srow[8] = {};

    for (int st = 0; st < 8; ++st) {
        const int buf = st & 1;
        size_t g0 = ((size_t)(b * S_LEN + posBase + st * 16 + pos_l)) * DM + h * DH + f0;
        size_t g1 = g0 + (size_t)8 * DM;
        uint4 ka = *(const uint4*)(kf + g0);
        uint4 kb = *(const uint4*)(kf + g1);
        uint4 va = *(const uint4*)(vv + g0);
        uint4 vb = *(const uint4*)(vv + g1);
        float kaf[8], kbf[8], vaf[8], vbf[8];
        unpack8(ka, kaf); unpack8(kb, kbf); unpack8(va, vaf); unpack8(vb, vbf);
#pragma unroll
        for (int j = 0; j < 8; ++j) srow[j] += kaf[j] + kbf[j];
        *(float4*)&Ks[wave][buf][pos_l][f0]         = make_float4(kaf[0], kaf[1], kaf[2], kaf[3]);
        *(float4*)&Ks[wave][buf][pos_l][f0 + 4]     = make_float4(kaf[4], kaf[5], kaf[6], kaf[7]);
        *(float4*)&Ks[wave][buf][pos_l + 8][f0]     = make_float4(kbf[0], kbf[1], kbf[2], kbf[3]);
        *(float4*)&Ks[wave][buf][pos_l + 8][f0 + 4] = make_float4(kbf[4], kbf[5], kbf[6], kbf[7]);
        *(float4*)&Vs[wave][buf][pos_l][f0]         = make_float4(vaf[0], vaf[1], vaf[2], vaf[3]);
        *(float4*)&Vs[wave][buf][pos_l][f0 + 4]     = make_float4(vaf[4], vaf[5], vaf[6], vaf[7]);
        *(float4*)&Vs[wave][buf][pos_l + 8][f0]     = make_float4(vbf[0], vbf[1], vbf[2], vbf[3]);
        *(float4*)&Vs[wave][buf][pos_l + 8][f0 + 4] = make_float4(vbf[4], vbf[5], vbf[6], vbf[7]);
#pragma unroll 4
        for (int q = 0; q < 16; ++q) {
            float4 a0 = *(const float4*)&Ks[wave][buf][q][r0];
            float4 a1 = *(const float4*)&Ks[wave][buf][q][r0 + 4];
            float4 b0 = *(const float4*)&Vs[wave][buf][q][c0];
            float4 b1 = *(const float4*)&Vs[wave][buf][q][c0 + 4];
            float aa[8] = {a0.x, a0.y, a0.z, a0.w, a1.x, a1.y, a1.z, a1.w};
            float bb[8] = {b0.x, b0.y, b0.z, b0.w, b1.x, b1.y, b1.z, b1.w};
#pragma unroll
            for (int i = 0; i < 8; ++i)
#pragma unroll
                for (int j = 0; j < 8; ++j)
                    acc[i][j] += aa[i] * bb[j];
        }
    }

#pragma unroll
    for (int j = 0; j < 8; ++j) {
        srow[j] += __shfl_xor(srow[j], 8);
        srow[j] += __shfl_xor(srow[j], 16);
        srow[j] += __shfl_xor(srow[j], 32);
    }

    __syncthreads();
    float* red = smem;
    float* ksred = smem + 16384;
#pragma unroll
    for (int j = 0; j < 8; ++j) {
        *(float4*)&red[wave * 4096 + (c0 + j) * 64 + r0] =
            make_float4(acc[0][j], acc[1][j], acc[2][j], acc[3][j]);
        *(float4*)&red[wave * 4096 + (c0 + j) * 64 + r0 + 4] =
            make_float4(acc[4][j], acc[5][j], acc[6][j], acc[7][j]);
    }
    if (pos_l == 0) {
        *(float4*)&ksred[wave * 64 + f0]     = make_float4(srow[0], srow[1], srow[2], srow[3]);
        *(float4*)&ksred[wave * 64 + f0 + 4] = make_float4(srow[4], srow[5], srow[6], srow[7]);
    }
    __syncthreads();

    float* outp = kv_part + ((size_t)bh * 4 + blk) * 4096;
    const int base = tid * 16;
#pragma unroll
    for (int g = 0; g < 4; ++g) {
        float4 s0 = *(const float4*)&red[base + g * 4];
        float4 s1 = *(const float4*)&red[4096 + base + g * 4];
        float4 s2 = *(const float4*)&red[8192 + base + g * 4];
        float4 s3 = *(const float4*)&red[12288 + base + g * 4];
        float4 o = make_float4(s0.x + s1.x + s2.x + s3.x,
                               s0.y + s1.y + s2.y + s3.y,
                               s0.z + s1.z + s2.z + s3.z,
                               s0.w + s1.w + s2.w + s3.w);
        *(float4*)&outp[base + g * 4] = o;
    }
    if (tid < 64) {
        float t = ksred[tid] + ksred[64 + tid] + ksred[128 + tid] + ksred[192 + tid];
        ksum_part[((size_t)bh * 4 + blk) * 64 + tid] = t;
    }
}

// -------- attend: reduce 4 kv partials + MFMA (qf @ kv) / denom -----------
__global__ __launch_bounds__(256) void attend_mfma(
    const unsigned short* __restrict__ qf, const float* __restrict__ kv_part,
    const float* __restrict__ ksum_part, unsigned short* __restrict__ att)
{
    const int sBase = blockIdx.x * 128;
    const int bh = blockIdx.y;
    const int b = bh >> 4, h = bh & 15;

    __shared__ __align__(16) unsigned short Qs[128 * 64];
    __shared__ __align__(16) unsigned short Ts[64 * 64];
    __shared__ __align__(16) float ks_s[DH];
    __shared__ float den_s[128];

    const int tid = threadIdx.x;
    const int wave = tid >> 6, lane = tid & 63;
    const int quad = lane >> 4, lm = lane & 15;

#pragma unroll
    for (int i = 0; i < 4; ++i) {
        int slot = (wave * 4 + i) * 64 + lane;
        int r = slot >> 3;
        int c = (slot & 7) ^ (r & 7);
        const unsigned short* src =
            qf + ((size_t)(b * S_LEN + sBase + r)) * DM + h * DH + c * 8;
        load16(src, Qs + (size_t)(wave * 4 + i) * 512);
    }

    {
        const int e = tid >> 2, c2 = tid & 3;
        const float* kp = kv_part + (size_t)bh * 4 * 4096 + e * 64 + c2 * 16;
        float s[16];
#pragma unroll
        for (int g = 0; g < 4; ++g) {
            float4 p0 = *(const float4*)(kp + g * 4);
            float4 p1 = *(const float4*)(kp + 4096 + g * 4);
            float4 p2 = *(const float4*)(kp + 8192 + g * 4);
            float4 p3 = *(const float4*)(kp + 12288 + g * 4);
            s[g * 4 + 0] = p0.x + p1.x + p2.x + p3.x;
            s[g * 4 + 1] = p0.y + p1.y + p2.y + p3.y;
            s[g * 4 + 2] = p0.z + p1.z + p2.z + p3.z;
            s[g * 4 + 3] = p0.w + p1.w + p2.w + p3.w;
        }
        unsigned short us[16];
#pragma unroll
        for (int i = 0; i < 16; ++i) us[i] = f2bf(s[i]);
        uint4 lo, hi;
        lo.x = (unsigned)us[0]  | ((unsigned)us[1]  << 16);
        lo.y = (unsigned)us[2]  | ((unsigned)us[3]  << 16);
        lo.z = (unsigned)us[4]  | ((unsigned)us[5]  << 16);
        lo.w = (unsigned)us[6]  | ((unsigned)us[7]  << 16);
        hi.x = (unsigned)us[8]  | ((unsigned)us[9]  << 16);
        hi.y = (unsigned)us[10] | ((unsigned)us[11] << 16);
        hi.z = (unsigned)us[12] | ((unsigned)us[13] << 16);
        hi.w = (unsigned)us[14] | ((unsigned)us[15] << 16);
        const int cL = c2 * 2, cH = c2 * 2 + 1;
        *(uint4*)(Ts + (size_t)(e * 8 + (cL ^ (e & 7))) * 8) = lo;
        *(uint4*)(Ts + (size_t)(e * 8 + (cH ^ (e & 7))) * 8) = hi;
    }
    if (tid < 64) {
        const float* kq = ksum_part + (size_t)bh * 4 * 64 + tid;
        ks_s[tid] = kq[0] + kq[64] + kq[128] + kq[192];
    }
    __syncthreads();

    if (tid < 128) {
        const int r = tid;
        float d = 0.f;
#pragma unroll
        for (int cxx = 0; cxx < 8; ++cxx) {
            int slot = r * 8 + (cxx ^ (r & 7));
            uint4 u = *(const uint4*)(Qs + slot * 8);
            float f[8]; unpack8(u, f);
            const float* kss = &ks_s[cxx * 8];
#pragma unroll
            for (int j = 0; j < 8; ++j) d += f[j] * kss[j];
        }
        den_s[r] = fmaxf(d, EPS);
    }
    __syncthreads();

    f32x4 acc[2][4];
#pragma unroll
    for (int ti = 0; ti < 2; ++ti)
#pragma unroll
        for (int tj = 0; tj < 4; ++tj)
            acc[ti][tj] = (f32x4){0.f, 0.f, 0.f, 0.f};

#pragma unroll
    for (int ks_i = 0; ks_i < 2; ++ks_i) {
        bf16x8 aF[2], bF[4];
#pragma unroll
        for (int ti = 0; ti < 2; ++ti) {
            int r = wave * 32 + ti * 16 + lm;
            int cx = (ks_i * 4 + quad) ^ (r & 7);
            aF[ti] = *(const bf16x8*)(Qs + (r * 8 + cx) * 8);
        }
#pragma unroll
        for (int tj = 0; tj < 4; ++tj) {
            int e = tj * 16 + lm;
            int cx = (ks_i * 4 + quad) ^ (e & 7);
            bF[tj] = *(const bf16x8*)(Ts + (e * 8 + cx) * 8);
        }
#pragma unroll
        for (int ti = 0; ti < 2; ++ti)
#pragma unroll
            for (int tj = 0; tj < 4; ++tj)
                acc[ti][tj] = __builtin_amdgcn_mfma_f32_16x16x32_bf16(aF[ti], bF[tj], acc[ti][tj], 0, 0, 0);
    }

#pragma unroll
    for (int ti = 0; ti < 2; ++ti) {
        const int rloc0 = wave * 32 + ti * 16 + quad * 4;
#pragma unroll
        for (int reg = 0; reg < 4; ++reg) {
            float inv = 1.0f / den_s[rloc0 + reg];
            unsigned short* dst =
                att + ((size_t)(b * S_LEN + sBase + rloc0 + reg)) * DM + h * DH;
#pragma unroll
            for (int tj = 0; tj < 4; ++tj)
                dst[tj * 16 + lm] = f2bf(acc[ti][tj][reg] * inv);
        }
    }
}

extern "C" void kernel_launch(void* const* d_in, const int* in_sizes, int n_in,
                              void* d_out, int out_size, void* d_ws, size_t ws_size,
                              hipStream_t stream) {
    const float* x  = (const float*)d_in[0];
    const float* wq = (const float*)d_in[1];
    const float* bq = (const float*)d_in[2];
    const float* wk = (const float*)d_in[3];
    const float* bk = (const float*)d_in[4];
    const float* wv = (const float*)d_in[5];
    const float* bv = (const float*)d_in[6];
    const float* wo = (const float*)d_in[7];
    const float* bo = (const float*)d_in[8];
    float* out = (float*)d_out;

    const size_t ND  = (size_t)BATCH * S_LEN * DM;  // 4,194,304
    const size_t NDW = (size_t)DM * DM;             // 1,048,576
    const int BH = BATCH * NH;                      // 32

    unsigned short* x_bf   = (unsigned short*)d_ws;
    unsigned short* wq_bf  = x_bf + ND;
    unsigned short* wk_bf  = wq_bf + NDW;
    unsigned short* wv_bf  = wk_bf + NDW;
    unsigned short* wo_bf  = wv_bf + NDW;
    unsigned short* qf_bf  = wo_bf + NDW;
    unsigned short* kf_bf  = qf_bf + ND;
    unsigned short* vv_bf  = kf_bf + ND;
    unsigned short* att_bf = vv_bf + ND;
    float* kv_part   = (float*)(att_bf + ND);
    float* ksum_part = kv_part + (size_t)BH * 4 * 4096;

    const int M = BATCH * S_LEN;  // 4096

    // 1. fp32 -> bf16
    cvt_flat<<<4096, 256, 0, stream>>>(x, wq, wk, wv, wo,
                                       x_bf, wq_bf, wk_bf, wv_bf, wo_bf);

    // 2. q/k/v projections (elu+1 on q,k), BK=64
    gemm_qkv<<<dim3(DM / 128, M / 128, 3), 256, 0, stream>>>(
        x_bf, wq_bf, wk_bf, wv_bf, bq, bk, bv,
        qf_bf, kf_bf, vv_bf, M, DM, DM, 0b011);

    // 3. kv partials
    kv_part_kernel<<<dim3(BH, 4), 256, 0, stream>>>(kf_bf, vv_bf, kv_part, ksum_part);

    // 4. attend
    attend_mfma<<<dim3(S_LEN / 128, BH), 256, 0, stream>>>(qf_bf, kv_part, ksum_part, att_bf);

    // 5. output projection, BK=64
    gemm_out<<<dim3(DM / 128, M / 64), 256, 0, stream>>>(
        att_bf, wo_bf, bo, out, M, DM, DM);
}